// Round 2
// baseline (311.637 us; speedup 1.0000x reference)
//
#include <hip/hip_runtime.h>
#include <math.h>

typedef __attribute__((ext_vector_type(8))) short short8;
typedef __attribute__((ext_vector_type(4))) float floatx4;

__device__ __forceinline__ unsigned short bf16r(float f) {
  union { float f; unsigned int u; } v; v.f = f;
  unsigned int u = v.u;
  return (unsigned short)((u + 0x7fffu + ((u >> 16) & 1u)) >> 16);
}
// round-half-up pack (sampling path; 2 ops)
__device__ __forceinline__ unsigned int bf16h(float f) {
  union { float f; unsigned int u; } v; v.f = f;
  return (v.u + 0x8000u) >> 16;
}
__device__ __forceinline__ float bf2f(unsigned int u) {
  union { unsigned int u; float f; } v; v.u = u << 16; return v.f;
}

// ---------------------------------------------------------------------------
// K0: weight prep (bf16, MFMA-frag layouts) + fused tables
// ---------------------------------------------------------------------------
__global__ __launch_bounds__(256) void k_prep(
    const float* __restrict__ w_dcn, const float* __restrict__ w_off,
    const float* __restrict__ b_dcn,
    const float* __restrict__ bn_g, const float* __restrict__ bn_b,
    const float* __restrict__ bn_m, const float* __restrict__ bn_v,
    const float* __restrict__ w_up, const float* __restrict__ w1x1,
    unsigned short* __restrict__ wt_dcn, unsigned short* __restrict__ wt_off,
    float* __restrict__ vtab, float* __restrict__ bntab) {
  int e = blockIdx.x * 256 + threadIdx.x;
  if (e < 294912) {
    int cc = e & 31, o = (e >> 5) & 127, s = e >> 12;
    int k = s % 9, cg = s / 9, c = cg * 32 + cc;
    wt_dcn[e] = bf16r(w_dcn[(o * 256 + c) * 9 + k]);
  }
  if (e < 73728) {
    int cc = e & 31, oc = (e >> 5) & 31, s = e >> 10;
    int k = s % 9, cg = s / 9, c = cg * 32 + cc;
    wt_off[e] = (oc < 27) ? bf16r(w_off[(oc * 256 + c) * 9 + k]) : (unsigned short)0;
  }
  if (e < 2048) {
    int o = e >> 4;
    vtab[e] = w1x1[o] * w_up[e];
  }
  if (e < 128) {
    float g = bn_g[e] * rsqrtf(bn_v[e] + 1e-5f);
    bntab[e] = g;
    bntab[128 + e] = (b_dcn[e] - bn_m[e]) * g + bn_b[e];
  }
}

// ---------------------------------------------------------------------------
// K0b: x (fp32 NCHW) -> xT (bf16, [b][pixel][c]) via LDS tile transpose
// XCD-swizzled: batch b -> XCD b (blockIdx % 8), so xT lands in the home L2.
// ---------------------------------------------------------------------------
__global__ __launch_bounds__(256) void k_xt(
    const float* __restrict__ x, unsigned short* __restrict__ xT) {
  __shared__ unsigned short sx[32 * 264];
  int b = blockIdx.x & 7, px0 = ((blockIdx.x >> 3) & 127) * 32;
  int t = threadIdx.x;
  int px = t & 31, cg = t >> 5;
  const float* xsrc = x + (((size_t)(b * 256 + cg * 32)) << 12) + px0 + px;
#pragma unroll
  for (int cc = 0; cc < 32; ++cc)
    sx[px * 264 + cg * 32 + cc] = bf16r(xsrc[(size_t)cc << 12]);
  __syncthreads();
#pragma unroll
  for (int j = 0; j < 4; ++j) {
    int unit = t + j * 256;
    int p = unit >> 5, chunk = unit & 31;
    uint4 v = *(const uint4*)&sx[p * 264 + chunk * 8];
    *(uint4*)&xT[((size_t)((b << 12) + px0 + p)) * 256 + chunk * 8] = v;
  }
}

// ---------------------------------------------------------------------------
// K1: offset conv via MFMA, zero LDS / zero barriers, batched loads (MLP).
// XCD-swizzled: batch b -> XCD b, xT gathers hit the home L2.
// ---------------------------------------------------------------------------
__global__ __launch_bounds__(256, 2) void k_offconv(
    const unsigned short* __restrict__ xT, const unsigned short* __restrict__ wt_off,
    const float* __restrict__ b_off, unsigned short* __restrict__ om) {
  int b = blockIdx.x & 7, row = blockIdx.x >> 3;
  int t = threadIdx.x, lane = t & 63, wvx = t >> 6;
  int l15 = lane & 15, quad = lane >> 4;
  int xcol = wvx * 16 + l15;
  const unsigned short* xb = xT + (((size_t)b) << 12) * 256;
  const short8 zz = {0, 0, 0, 0, 0, 0, 0, 0};

  // hoist per-k pixel index + validity (same for every cg)
  int pixk[9]; bool vk[9];
#pragma unroll
  for (int k = 0; k < 9; ++k) {
    int yy = row + k / 3 - 1, xx = xcol + k % 3 - 1;
    vk[k] = ((unsigned)yy < 64u) & ((unsigned)xx < 64u);
    pixk[k] = vk[k] ? (yy * 64 + xx) : 0;
  }

  floatx4 acc[2];
  acc[0] = (floatx4){0.f, 0.f, 0.f, 0.f};
  acc[1] = (floatx4){0.f, 0.f, 0.f, 0.f};

  for (int cg = 0; cg < 8; ++cg) {
    int cb = cg * 32 + quad * 8;
    short8 bx[9];
#pragma unroll
    for (int k = 0; k < 9; ++k) {             // 9 independent loads in flight
      short8 v = *(const short8*)&xb[(size_t)pixk[k] * 256 + cb];
      bx[k] = vk[k] ? v : zz;
    }
#pragma unroll
    for (int k = 0; k < 9; ++k) {
      const unsigned short* wp = wt_off + (size_t)(cg * 9 + k) * 1024;
      short8 a0 = *(const short8*)&wp[l15 * 32 + quad * 8];
      short8 a1 = *(const short8*)&wp[(16 + l15) * 32 + quad * 8];
      acc[0] = __builtin_amdgcn_mfma_f32_16x16x32_bf16(a0, bx[k], acc[0], 0, 0, 0);
      acc[1] = __builtin_amdgcn_mfma_f32_16x16x32_bf16(a1, bx[k], acc[1], 0, 0, 0);
    }
  }
#pragma unroll
  for (int ot = 0; ot < 2; ++ot)
#pragma unroll
    for (int r = 0; r < 4; ++r) {
      int o = ot * 16 + quad * 4 + r;
      if (o < 27)
        om[(((size_t)(b * 27 + o)) << 12) + row * 64 + xcol] = bf16r(acc[ot][r] + b_off[o]);
    }
}

// ---------------------------------------------------------------------------
// K2: DCNv2 via MFMA + fused BN/ReLU + fused (upsample x 1x1) -> R.
// ZERO-BARRIER main loop: W A-fragments load straight from L2 to registers
// (wt is 576 KB, L2-resident, broadcast-read by all blocks) -- no LDS W
// staging, no per-phase __syncthreads/waitcnt/sched walls.  The 4 waves of
// a block run as fully independent streams, so VALU (sampling), MFMA,
// VMEM-gather and LDS-read time overlaps across the 8 resident waves/CU
// instead of serializing phase-by-phase.
// Tap data still prefetched one phase ahead (reg-level, cross-phase ILP).
// XCD-swizzled: batch b -> XCD b (per-batch working set ~3.1 MB < 4 MiB L2).
// ---------------------------------------------------------------------------
__global__ __launch_bounds__(256, 2) void k_dcn(
    const unsigned short* __restrict__ xT, const unsigned short* __restrict__ wt,
    const unsigned short* __restrict__ om, const float* __restrict__ vtab,
    const float* __restrict__ bntab, float* __restrict__ R) {
  int b = blockIdx.x & 7, row = blockIdx.x >> 3;
  __shared__ ushort4 s_ti[576];
  __shared__ float4 s_tw[576];
  __shared__ float sv[128 * 17];   // stride 17: quads (o += 4) land on
  __shared__ float sbn[256];       // different banks -> conflict-free epilogue
  int t = threadIdx.x, lane = t & 63, wvx = t >> 6;
  int l15 = lane & 15, quad = lane >> 4;

  // prologue: taps = 4 clamped pixel indices + 4 mask-folded weights per (k,px)
  for (int i = t; i < 576; i += 256) {
    int k = i >> 6, p = i & 63;
    float o1 = bf2f(om[(((size_t)(b * 27 + k)) << 12) + row * 64 + p]);
    float o2 = bf2f(om[(((size_t)(b * 27 + 9 + k)) << 12) + row * 64 + p]);
    float mv = bf2f(om[(((size_t)(b * 27 + 18 + k)) << 12) + row * 64 + p]);
    float m = 1.f / (1.f + __expf(-mv));
    float py = (float)(row + k / 3 - 1) + o1;
    float pxf = (float)(p + (k % 3) - 1) + o2;
    float fy = floorf(py), fx = floorf(pxf);
    int iy = (int)fy, ix = (int)fx;
    float wy1 = py - fy, wy0 = 1.f - wy1;
    float wx1 = pxf - fx, wx0 = 1.f - wx1;
    bool y0ok = (iy >= 0) & (iy < 64), y1ok = (iy >= -1) & (iy < 63);
    bool x0ok = (ix >= 0) & (ix < 64), x1ok = (ix >= -1) & (ix < 63);
    int iy0 = min(max(iy, 0), 63), iy1 = min(max(iy + 1, 0), 63);
    int ix0 = min(max(ix, 0), 63), ix1 = min(max(ix + 1, 0), 63);
    s_ti[i] = make_ushort4((unsigned short)(iy0 * 64 + ix0), (unsigned short)(iy0 * 64 + ix1),
                           (unsigned short)(iy1 * 64 + ix0), (unsigned short)(iy1 * 64 + ix1));
    float4 w;
    w.x = (y0ok && x0ok) ? m * wy0 * wx0 : 0.f;
    w.y = (y0ok && x1ok) ? m * wy0 * wx1 : 0.f;
    w.z = (y1ok && x0ok) ? m * wy1 * wx0 : 0.f;
    w.w = (y1ok && x1ok) ? m * wy1 * wx1 : 0.f;
    s_tw[i] = w;
  }
  // epilogue tables staged here too (read-only until epilogue)
  for (int i = t; i < 2048; i += 256) sv[(i >> 4) * 17 + (i & 15)] = vtab[i];
  if (t < 256) sbn[t] = bntab[t];
  __syncthreads();   // s_ti/s_tw/sv/sbn ready (read-only hereafter)

  int px = wvx * 16 + l15;
  const unsigned short* xb = xT + (((size_t)b) << 12) * 256;

  floatx4 acc[8];
#pragma unroll
  for (int i = 0; i < 8; ++i) acc[i] = (floatx4){0.f, 0.f, 0.f, 0.f};

  // tap raw data for current phase (prefetched one phase ahead)
  uint4 traw[12];   // [kk][tap]
  {
    int cbase = quad * 8;                       // phase 0: cg=0
#pragma unroll
    for (int kk = 0; kk < 3; ++kk) {
      ushort4 ti = s_ti[(kk << 6) + px];        // phase 0: k = kk
      traw[kk * 4 + 0] = *(const uint4*)&xb[(size_t)ti.x * 256 + cbase];
      traw[kk * 4 + 1] = *(const uint4*)&xb[(size_t)ti.y * 256 + cbase];
      traw[kk * 4 + 2] = *(const uint4*)&xb[(size_t)ti.z * 256 + cbase];
      traw[kk * 4 + 3] = *(const uint4*)&xb[(size_t)ti.w * 256 + cbase];
    }
  }

  for (int phase = 0; phase < 24; ++phase) {
    const unsigned short* wp = wt + (size_t)phase * 12288;
    int nphase = phase + 1;
    int ncbase = (nphase / 3) * 32 + quad * 8;

#pragma unroll
    for (int kk = 0; kk < 3; ++kk) {
      int k = (phase % 3) * 3 + kk;
      // issue A-fragment loads first: L2-resident, latency hides under the
      // sampling VALU below
      short8 af[8];
#pragma unroll
      for (int ot = 0; ot < 8; ++ot)
        af[ot] = *(const short8*)&wp[(kk * 128 + ot * 16 + l15) * 32 + quad * 8];
      // compute bfr from prefetched taps
      float4 tw = s_tw[(k << 6) + px];
      union { uint4 u; short8 s; } x0, x1, x2, x3;
      x0.u = traw[kk * 4 + 0]; x1.u = traw[kk * 4 + 1];
      x2.u = traw[kk * 4 + 2]; x3.u = traw[kk * 4 + 3];
      // prefetch taps for next phase into same slots (consumed above)
      if (phase < 23) {
        int nk = (nphase % 3) * 3 + kk;
        ushort4 ti = s_ti[(nk << 6) + px];
        traw[kk * 4 + 0] = *(const uint4*)&xb[(size_t)ti.x * 256 + ncbase];
        traw[kk * 4 + 1] = *(const uint4*)&xb[(size_t)ti.y * 256 + ncbase];
        traw[kk * 4 + 2] = *(const uint4*)&xb[(size_t)ti.z * 256 + ncbase];
        traw[kk * 4 + 3] = *(const uint4*)&xb[(size_t)ti.w * 256 + ncbase];
      }
      float r[8];
#pragma unroll
      for (int j = 0; j < 8; ++j)
        r[j] = tw.x * bf2f((unsigned short)x0.s[j]) + tw.y * bf2f((unsigned short)x1.s[j]) +
               tw.z * bf2f((unsigned short)x2.s[j]) + tw.w * bf2f((unsigned short)x3.s[j]);
      union { uint4 u; short8 s; } bu;
      bu.u = make_uint4(bf16h(r[0]) | (bf16h(r[1]) << 16), bf16h(r[2]) | (bf16h(r[3]) << 16),
                        bf16h(r[4]) | (bf16h(r[5]) << 16), bf16h(r[6]) | (bf16h(r[7]) << 16));
#pragma unroll
      for (int ot = 0; ot < 8; ++ot)
        acc[ot] = __builtin_amdgcn_mfma_f32_16x16x32_bf16(af[ot], bu.s, acc[ot], 0, 0, 0);
    }
  }

  // epilogue: BN+ReLU then R_t[px] = sum_o v[o][t]*yv, reduced over quads
  float rpart[16];
#pragma unroll
  for (int i = 0; i < 16; ++i) rpart[i] = 0.f;
#pragma unroll
  for (int ot = 0; ot < 8; ++ot)
#pragma unroll
    for (int r = 0; r < 4; ++r) {
      int o = ot * 16 + quad * 4 + r;
      float yv = fmaxf(acc[ot][r] * sbn[o] + sbn[128 + o], 0.f);
      const float* vp = &sv[o * 17];
#pragma unroll
      for (int tt = 0; tt < 16; ++tt) rpart[tt] += vp[tt] * yv;
    }
#pragma unroll
  for (int tt = 0; tt < 16; ++tt) {
    rpart[tt] += __shfl_xor(rpart[tt], 16, 64);
    rpart[tt] += __shfl_xor(rpart[tt], 32, 64);
  }
  size_t rbase = ((size_t)((b << 12) + row * 64 + px)) * 16;
#pragma unroll
  for (int j = 0; j < 4; ++j) R[rbase + quad * 4 + j] = rpart[quad * 4 + j];
}

// ---------------------------------------------------------------------------
// K3: upsample+1x1+sigmoid from R maps: 4 loads + sigmoid per output
// XCD-swizzled: batch b -> XCD b, R reads hit the home L2.
// ---------------------------------------------------------------------------
__global__ __launch_bounds__(256) void k_upb(
    const float* __restrict__ R, float* __restrict__ out) {
  int b = blockIdx.x & 7, sub = blockIdx.x >> 3;
  int inner = sub * 256 + threadIdx.x;        // 0..16383
  int X = inner & 127, Y = inner >> 7;        // Y 0..127
  int i0, wu0, wu1, j0, wv0, wv1;
  if (Y & 1) { i0 = (Y - 1) >> 1; wu0 = 2; wu1 = 0; }
  else       { i0 = (Y - 2) / 2;  wu0 = 3; wu1 = 1; }
  if (X & 1) { j0 = (X - 1) >> 1; wv0 = 2; wv1 = 0; }
  else       { j0 = (X - 2) / 2;  wv0 = 3; wv1 = 1; }
  int i1 = i0 + 1, j1 = j0 + 1;
  float mi0 = ((unsigned)i0 < 64u) ? 1.f : 0.f;
  float mi1 = ((unsigned)i1 < 64u) ? 1.f : 0.f;
  float mj0 = ((unsigned)j0 < 64u) ? 1.f : 0.f;
  float mj1 = ((unsigned)j1 < 64u) ? 1.f : 0.f;
  int i0c = min(max(i0, 0), 63), i1c = min(max(i1, 0), 63);
  int j0c = min(max(j0, 0), 63), j1c = min(max(j1, 0), 63);
  const float* Rb = R + (((size_t)b) << 12) * 16;
  float s = mi0 * mj0 * Rb[(size_t)(i0c * 64 + j0c) * 16 + wu0 * 4 + wv0] +
            mi0 * mj1 * Rb[(size_t)(i0c * 64 + j1c) * 16 + wu0 * 4 + wv1] +
            mi1 * mj0 * Rb[(size_t)(i1c * 64 + j0c) * 16 + wu1 * 4 + wv0] +
            mi1 * mj1 * Rb[(size_t)(i1c * 64 + j1c) * 16 + wu1 * 4 + wv1];
  out[(b << 14) + inner] = 1.f / (1.f + __expf(-s));
}

// ---------------------------------------------------------------------------
extern "C" void kernel_launch(void* const* d_in, const int* in_sizes, int n_in,
                              void* d_out, int out_size, void* d_ws, size_t ws_size,
                              hipStream_t stream) {
  const float* x        = (const float*)d_in[0];
  const float* w_dcn    = (const float*)d_in[1];
  const float* b_dcn    = (const float*)d_in[2];
  const float* w_off    = (const float*)d_in[3];
  const float* b_off    = (const float*)d_in[4];
  const float* bn_gamma = (const float*)d_in[5];
  const float* bn_beta  = (const float*)d_in[6];
  const float* bn_mean  = (const float*)d_in[7];
  const float* bn_var   = (const float*)d_in[8];
  const float* w_up     = (const float*)d_in[9];
  const float* w_1x1    = (const float*)d_in[10];
  float* out = (float*)d_out;

  // ws layout in FLOAT units (21.39 MB total):
  float* ws = (float*)d_ws;
  unsigned short* xT     = (unsigned short*)ws;                    // 8388608 ush
  unsigned short* wt_dcn = (unsigned short*)(ws + 4194304);        //  294912 ush
  unsigned short* wt_off = (unsigned short*)(ws + 4341760);        //   73728 ush
  float* vtab            = ws + 4378624;                           //    2048 f
  float* bntab           = ws + 4380672;                           //     256 f
  unsigned short* om     = (unsigned short*)(ws + 4380928);        //  884736 ush
  float* R               = ws + 4823296;                           //  524288 f

  k_prep<<<1152, 256, 0, stream>>>(w_dcn, w_off, b_dcn, bn_gamma, bn_beta,
                                   bn_mean, bn_var, w_up, w_1x1,
                                   wt_dcn, wt_off, vtab, bntab);
  k_xt<<<1024, 256, 0, stream>>>(x, xT);
  k_offconv<<<512, 256, 0, stream>>>(xT, wt_off, b_off, om);
  k_dcn<<<512, 256, 0, stream>>>(xT, wt_dcn, om, vtab, bntab, R);
  k_upb<<<512, 256, 0, stream>>>(R, out);
}

// Round 3
// 185.376 us; speedup vs baseline: 1.6811x; 1.6811x over previous
//
#include <hip/hip_runtime.h>
#include <math.h>

typedef __attribute__((ext_vector_type(8))) short short8;
typedef __attribute__((ext_vector_type(4))) float floatx4;

__device__ __forceinline__ unsigned short bf16r(float f) {
  union { float f; unsigned int u; } v; v.f = f;
  unsigned int u = v.u;
  return (unsigned short)((u + 0x7fffu + ((u >> 16) & 1u)) >> 16);
}
// round-half-up pack (sampling path; 2 ops)
__device__ __forceinline__ unsigned int bf16h(float f) {
  union { float f; unsigned int u; } v; v.f = f;
  return (v.u + 0x8000u) >> 16;
}
__device__ __forceinline__ float bf2f(unsigned int u) {
  union { unsigned int u; float f; } v; v.u = u << 16; return v.f;
}
// async global->LDS DMA, 16B/lane; LDS dst = wave-uniform base + lane*16
__device__ __forceinline__ void glds16(const void* g, void* l) {
  __builtin_amdgcn_global_load_lds(
      (const __attribute__((address_space(1))) unsigned int*)g,
      (__attribute__((address_space(3))) unsigned int*)l, 16, 0, 0);
}

// ---------------------------------------------------------------------------
// K0: weight prep (bf16, MFMA-frag layouts) + fused tables
// wt_dcn layout is LANE-LINEAR per (s,ot) tile: element for wave-lane L lives
// at s*4096 + ot*512 + L*8 (+j).  ds_read_b128 in k_dcn is then a linear
// addr = base + lane*16B -> conflict-free (was an 8-way bank conflict:
// 5.77M SQ_LDS_BANK_CONFLICT/dispatch with the old (l15*64+quad*16) pattern).
// ---------------------------------------------------------------------------
__global__ __launch_bounds__(256) void k_prep(
    const float* __restrict__ w_dcn, const float* __restrict__ w_off,
    const float* __restrict__ b_dcn,
    const float* __restrict__ bn_g, const float* __restrict__ bn_b,
    const float* __restrict__ bn_m, const float* __restrict__ bn_v,
    const float* __restrict__ w_up, const float* __restrict__ w1x1,
    unsigned short* __restrict__ wt_dcn, unsigned short* __restrict__ wt_off,
    float* __restrict__ vtab, float* __restrict__ bntab) {
  int e = blockIdx.x * 256 + threadIdx.x;
  if (e < 294912) {
    int s = e >> 12;            // s = cg*9 + k  (72 tiles of 4096 ush)
    int r = e & 4095;
    int ot = r >> 9;            // 8 output-tiles of 512 ush
    int lane = (r >> 3) & 63;   // wave lane this element feeds
    int j = e & 7;
    int l15 = lane & 15, quad = lane >> 4;
    int o = ot * 16 + l15;
    int k = s % 9, cg = s / 9;
    int c = cg * 32 + quad * 8 + j;
    wt_dcn[e] = bf16r(w_dcn[(o * 256 + c) * 9 + k]);
  }
  if (e < 73728) {
    int cc = e & 31, oc = (e >> 5) & 31, s = e >> 10;
    int k = s % 9, cg = s / 9, c = cg * 32 + cc;
    wt_off[e] = (oc < 27) ? bf16r(w_off[(oc * 256 + c) * 9 + k]) : (unsigned short)0;
  }
  if (e < 2048) {
    int o = e >> 4;
    vtab[e] = w1x1[o] * w_up[e];
  }
  if (e < 128) {
    float g = bn_g[e] * rsqrtf(bn_v[e] + 1e-5f);
    bntab[e] = g;
    bntab[128 + e] = (b_dcn[e] - bn_m[e]) * g + bn_b[e];
  }
}

// ---------------------------------------------------------------------------
// K0b: x (fp32 NCHW) -> xT (bf16, [b][pixel][c]) via LDS tile transpose
// XCD-swizzled: batch b -> XCD b (blockIdx % 8), so xT lands in the home L2.
// ---------------------------------------------------------------------------
__global__ __launch_bounds__(256) void k_xt(
    const float* __restrict__ x, unsigned short* __restrict__ xT) {
  __shared__ unsigned short sx[32 * 264];
  int b = blockIdx.x & 7, px0 = ((blockIdx.x >> 3) & 127) * 32;
  int t = threadIdx.x;
  int px = t & 31, cg = t >> 5;
  const float* xsrc = x + (((size_t)(b * 256 + cg * 32)) << 12) + px0 + px;
#pragma unroll
  for (int cc = 0; cc < 32; ++cc)
    sx[px * 264 + cg * 32 + cc] = bf16r(xsrc[(size_t)cc << 12]);
  __syncthreads();
#pragma unroll
  for (int j = 0; j < 4; ++j) {
    int unit = t + j * 256;
    int p = unit >> 5, chunk = unit & 31;
    uint4 v = *(const uint4*)&sx[p * 264 + chunk * 8];
    *(uint4*)&xT[((size_t)((b << 12) + px0 + p)) * 256 + chunk * 8] = v;
  }
}

// ---------------------------------------------------------------------------
// K1: offset conv via MFMA, zero LDS / zero barriers, batched loads (MLP).
// XCD-swizzled: batch b -> XCD b, xT gathers hit the home L2.
// ---------------------------------------------------------------------------
__global__ __launch_bounds__(256, 2) void k_offconv(
    const unsigned short* __restrict__ xT, const unsigned short* __restrict__ wt_off,
    const float* __restrict__ b_off, unsigned short* __restrict__ om) {
  int b = blockIdx.x & 7, row = blockIdx.x >> 3;
  int t = threadIdx.x, lane = t & 63, wvx = t >> 6;
  int l15 = lane & 15, quad = lane >> 4;
  int xcol = wvx * 16 + l15;
  const unsigned short* xb = xT + (((size_t)b) << 12) * 256;
  const short8 zz = {0, 0, 0, 0, 0, 0, 0, 0};

  // hoist per-k pixel index + validity (same for every cg)
  int pixk[9]; bool vk[9];
#pragma unroll
  for (int k = 0; k < 9; ++k) {
    int yy = row + k / 3 - 1, xx = xcol + k % 3 - 1;
    vk[k] = ((unsigned)yy < 64u) & ((unsigned)xx < 64u);
    pixk[k] = vk[k] ? (yy * 64 + xx) : 0;
  }

  floatx4 acc[2];
  acc[0] = (floatx4){0.f, 0.f, 0.f, 0.f};
  acc[1] = (floatx4){0.f, 0.f, 0.f, 0.f};

  for (int cg = 0; cg < 8; ++cg) {
    int cb = cg * 32 + quad * 8;
    short8 bx[9];
#pragma unroll
    for (int k = 0; k < 9; ++k) {             // 9 independent loads in flight
      short8 v = *(const short8*)&xb[(size_t)pixk[k] * 256 + cb];
      bx[k] = vk[k] ? v : zz;
    }
#pragma unroll
    for (int k = 0; k < 9; ++k) {
      const unsigned short* wp = wt_off + (size_t)(cg * 9 + k) * 1024;
      short8 a0 = *(const short8*)&wp[l15 * 32 + quad * 8];
      short8 a1 = *(const short8*)&wp[(16 + l15) * 32 + quad * 8];
      acc[0] = __builtin_amdgcn_mfma_f32_16x16x32_bf16(a0, bx[k], acc[0], 0, 0, 0);
      acc[1] = __builtin_amdgcn_mfma_f32_16x16x32_bf16(a1, bx[k], acc[1], 0, 0, 0);
    }
  }
#pragma unroll
  for (int ot = 0; ot < 2; ++ot)
#pragma unroll
    for (int r = 0; r < 4; ++r) {
      int o = ot * 16 + quad * 4 + r;
      if (o < 27)
        om[(((size_t)(b * 27 + o)) << 12) + row * 64 + xcol] = bf16r(acc[ot][r] + b_off[o]);
    }
}

// ---------------------------------------------------------------------------
// K2: DCNv2 via MFMA + fused BN/ReLU + fused (upsample x 1x1) -> R.
// R0 structure (proven 93us): glds double-buffered W, ONE __syncthreads per
// phase, tap prefetch one phase ahead.  Plus this round:
//  - lane-linear W tiles -> conflict-free ds_read_b128 (see k_prep)
//  - zero-weight tap skip: wave-uniform __any(w!=0) guards skip both the
//    gather and the sampling FMAs for taps whose bilinear weight is 0
//    across the wave (exact: contribution would be 0).  Integral sampling
//    positions (e.g. zero offsets) make 3 of 4 taps zero.
// XCD-swizzled: batch b -> XCD b (per-batch working set ~3.1 MB < 4 MiB L2).
// ---------------------------------------------------------------------------
__global__ __launch_bounds__(256, 2) void k_dcn(
    const unsigned short* __restrict__ xT, const unsigned short* __restrict__ wt,
    const unsigned short* __restrict__ om, const float* __restrict__ vtab,
    const float* __restrict__ bntab, float* __restrict__ R) {
  int b = blockIdx.x & 7, row = blockIdx.x >> 3;
  __shared__ unsigned short sW[2 * 12288];   // 2 x 24576 B
  __shared__ ushort4 s_ti[576];
  __shared__ float4 s_tw[576];
  int t = threadIdx.x, lane = t & 63, wvx = t >> 6;
  int l15 = lane & 15, quad = lane >> 4;

  // prologue: taps = 4 clamped pixel indices + 4 mask-folded weights per (k,px)
  for (int i = t; i < 576; i += 256) {
    int k = i >> 6, p = i & 63;
    float o1 = bf2f(om[(((size_t)(b * 27 + k)) << 12) + row * 64 + p]);
    float o2 = bf2f(om[(((size_t)(b * 27 + 9 + k)) << 12) + row * 64 + p]);
    float mv = bf2f(om[(((size_t)(b * 27 + 18 + k)) << 12) + row * 64 + p]);
    float m = 1.f / (1.f + __expf(-mv));
    float py = (float)(row + k / 3 - 1) + o1;
    float pxf = (float)(p + (k % 3) - 1) + o2;
    float fy = floorf(py), fx = floorf(pxf);
    int iy = (int)fy, ix = (int)fx;
    float wy1 = py - fy, wy0 = 1.f - wy1;
    float wx1 = pxf - fx, wx0 = 1.f - wx1;
    bool y0ok = (iy >= 0) & (iy < 64), y1ok = (iy >= -1) & (iy < 63);
    bool x0ok = (ix >= 0) & (ix < 64), x1ok = (ix >= -1) & (ix < 63);
    int iy0 = min(max(iy, 0), 63), iy1 = min(max(iy + 1, 0), 63);
    int ix0 = min(max(ix, 0), 63), ix1 = min(max(ix + 1, 0), 63);
    s_ti[i] = make_ushort4((unsigned short)(iy0 * 64 + ix0), (unsigned short)(iy0 * 64 + ix1),
                           (unsigned short)(iy1 * 64 + ix0), (unsigned short)(iy1 * 64 + ix1));
    float4 w;
    w.x = (y0ok && x0ok) ? m * wy0 * wx0 : 0.f;
    w.y = (y0ok && x1ok) ? m * wy0 * wx1 : 0.f;
    w.z = (y1ok && x0ok) ? m * wy1 * wx0 : 0.f;
    w.w = (y1ok && x1ok) ? m * wy1 * wx1 : 0.f;
    s_tw[i] = w;
  }
  __syncthreads();   // s_ti/s_tw ready (read-only hereafter)

  int px = wvx * 16 + l15;
  const unsigned short* xb = xT + (((size_t)b) << 12) * 256;
  const uint4 z4 = make_uint4(0u, 0u, 0u, 0u);

  floatx4 acc[8];
#pragma unroll
  for (int i = 0; i < 8; ++i) acc[i] = (floatx4){0.f, 0.f, 0.f, 0.f};

  // tap raw data for current phase (prefetched one phase ahead)
  uint4 traw[12];   // [kk][tap]
  {
    int cbase = quad * 8;                       // phase 0: cg=0
#pragma unroll
    for (int kk = 0; kk < 3; ++kk) {
      ushort4 ti = s_ti[(kk << 6) + px];        // phase 0: k = kk
      float4 twn = s_tw[(kk << 6) + px];
      uint4 t0 = z4, t1 = z4, t2 = z4, t3 = z4;
      if (__any(twn.x != 0.f)) t0 = *(const uint4*)&xb[(size_t)ti.x * 256 + cbase];
      if (__any(twn.y != 0.f)) t1 = *(const uint4*)&xb[(size_t)ti.y * 256 + cbase];
      if (__any(twn.z != 0.f)) t2 = *(const uint4*)&xb[(size_t)ti.z * 256 + cbase];
      if (__any(twn.w != 0.f)) t3 = *(const uint4*)&xb[(size_t)ti.w * 256 + cbase];
      traw[kk * 4 + 0] = t0; traw[kk * 4 + 1] = t1;
      traw[kk * 4 + 2] = t2; traw[kk * 4 + 3] = t3;
    }
  }
  {  // glds W(phase 0) -> buf 0
    const unsigned short* wsrc = wt;
#pragma unroll
    for (int i = 0; i < 6; ++i) {
      int blk = wvx * 6 + i;
      glds16(wsrc + (size_t)blk * 512 + lane * 8, &sW[blk * 512]);
    }
  }
  __syncthreads();   // buf0 complete (vmcnt drain) + taps in regs

  int lofs = lane * 8;   // lane-linear A-frag offset (ushorts)

  for (int phase = 0; phase < 24; ++phase) {
    unsigned short* buf = sW + (phase & 1) * 12288;
    unsigned short* nbuf = sW + ((phase + 1) & 1) * 12288;
    // issue next W DMA first (overlaps everything below)
    if (phase < 23) {
      const unsigned short* wsrc = wt + (size_t)(phase + 1) * 12288;
#pragma unroll
      for (int i = 0; i < 6; ++i) {
        int blk = wvx * 6 + i;
        glds16(wsrc + (size_t)blk * 512 + lane * 8, &nbuf[blk * 512]);
      }
    }
    int nphase = phase + 1;
    int ncbase = (nphase / 3) * 32 + quad * 8;

#pragma unroll
    for (int kk = 0; kk < 3; ++kk) {
      int k = (phase % 3) * 3 + kk;
      // current-phase tap weights + raw data (prefetched)
      float4 tw = s_tw[(k << 6) + px];
      union { uint4 u; short8 s; } x0, x1, x2, x3;
      x0.u = traw[kk * 4 + 0]; x1.u = traw[kk * 4 + 1];
      x2.u = traw[kk * 4 + 2]; x3.u = traw[kk * 4 + 3];
      // prefetch taps for next phase into same slots (consumed above),
      // skipping gathers whose weights are zero across the wave
      if (phase < 23) {
        int nk = (nphase % 3) * 3 + kk;
        ushort4 ti = s_ti[(nk << 6) + px];
        float4 twn = s_tw[(nk << 6) + px];
        uint4 t0 = z4, t1 = z4, t2 = z4, t3 = z4;
        if (__any(twn.x != 0.f)) t0 = *(const uint4*)&xb[(size_t)ti.x * 256 + ncbase];
        if (__any(twn.y != 0.f)) t1 = *(const uint4*)&xb[(size_t)ti.y * 256 + ncbase];
        if (__any(twn.z != 0.f)) t2 = *(const uint4*)&xb[(size_t)ti.z * 256 + ncbase];
        if (__any(twn.w != 0.f)) t3 = *(const uint4*)&xb[(size_t)ti.w * 256 + ncbase];
        traw[kk * 4 + 0] = t0; traw[kk * 4 + 1] = t1;
        traw[kk * 4 + 2] = t2; traw[kk * 4 + 3] = t3;
      }
      // sampling: tap0 always; taps 1-3 skipped when wave-uniformly zero
      float r[8];
#pragma unroll
      for (int j = 0; j < 8; ++j) r[j] = tw.x * bf2f((unsigned short)x0.s[j]);
      if (__any(tw.y != 0.f)) {
#pragma unroll
        for (int j = 0; j < 8; ++j) r[j] += tw.y * bf2f((unsigned short)x1.s[j]);
      }
      if (__any(tw.z != 0.f)) {
#pragma unroll
        for (int j = 0; j < 8; ++j) r[j] += tw.z * bf2f((unsigned short)x2.s[j]);
      }
      if (__any(tw.w != 0.f)) {
#pragma unroll
        for (int j = 0; j < 8; ++j) r[j] += tw.w * bf2f((unsigned short)x3.s[j]);
      }
      union { uint4 u; short8 s; } bu;
      bu.u = make_uint4(bf16h(r[0]) | (bf16h(r[1]) << 16), bf16h(r[2]) | (bf16h(r[3]) << 16),
                        bf16h(r[4]) | (bf16h(r[5]) << 16), bf16h(r[6]) | (bf16h(r[7]) << 16));
      // MFMA for this kk; lane-linear A-frag reads (conflict-free)
      const unsigned short* bk = buf + kk * 4096 + lofs;
#pragma unroll
      for (int ot = 0; ot < 8; ++ot) {
        short8 af = *(const short8*)&bk[ot * 512];
        acc[ot] = __builtin_amdgcn_mfma_f32_16x16x32_bf16(af, bu.s, acc[ot], 0, 0, 0);
      }
    }
    __syncthreads();  // drains glds(next) + all waves done reading buf
  }

  // epilogue: BN+ReLU then R_t[px] = sum_o v[o][t]*yv, reduced over quads
  float* sv = (float*)sW;          // 128*17 vtab (stride 17: conflict-free) + bn
  float* sbn = sv + 2176;
  for (int i = t; i < 2048; i += 256) sv[(i >> 4) * 17 + (i & 15)] = vtab[i];
  if (t < 256) sbn[t] = bntab[t];
  __syncthreads();

  float rpart[16];
#pragma unroll
  for (int i = 0; i < 16; ++i) rpart[i] = 0.f;
#pragma unroll
  for (int ot = 0; ot < 8; ++ot)
#pragma unroll
    for (int r = 0; r < 4; ++r) {
      int o = ot * 16 + quad * 4 + r;
      float yv = fmaxf(acc[ot][r] * sbn[o] + sbn[128 + o], 0.f);
      const float* vp = &sv[o * 17];
#pragma unroll
      for (int tt = 0; tt < 16; ++tt) rpart[tt] += vp[tt] * yv;
    }
#pragma unroll
  for (int tt = 0; tt < 16; ++tt) {
    rpart[tt] += __shfl_xor(rpart[tt], 16, 64);
    rpart[tt] += __shfl_xor(rpart[tt], 32, 64);
  }
  size_t rbase = ((size_t)((b << 12) + row * 64 + px)) * 16;
#pragma unroll
  for (int j = 0; j < 4; ++j) R[rbase + quad * 4 + j] = rpart[quad * 4 + j];
}

// ---------------------------------------------------------------------------
// K3: upsample+1x1+sigmoid from R maps: 4 loads + sigmoid per output
// XCD-swizzled: batch b -> XCD b, R reads hit the home L2.
// ---------------------------------------------------------------------------
__global__ __launch_bounds__(256) void k_upb(
    const float* __restrict__ R, float* __restrict__ out) {
  int b = blockIdx.x & 7, sub = blockIdx.x >> 3;
  int inner = sub * 256 + threadIdx.x;        // 0..16383
  int X = inner & 127, Y = inner >> 7;        // Y 0..127
  int i0, wu0, wu1, j0, wv0, wv1;
  if (Y & 1) { i0 = (Y - 1) >> 1; wu0 = 2; wu1 = 0; }
  else       { i0 = (Y - 2) / 2;  wu0 = 3; wu1 = 1; }
  if (X & 1) { j0 = (X - 1) >> 1; wv0 = 2; wv1 = 0; }
  else       { j0 = (X - 2) / 2;  wv0 = 3; wv1 = 1; }
  int i1 = i0 + 1, j1 = j0 + 1;
  float mi0 = ((unsigned)i0 < 64u) ? 1.f : 0.f;
  float mi1 = ((unsigned)i1 < 64u) ? 1.f : 0.f;
  float mj0 = ((unsigned)j0 < 64u) ? 1.f : 0.f;
  float mj1 = ((unsigned)j1 < 64u) ? 1.f : 0.f;
  int i0c = min(max(i0, 0), 63), i1c = min(max(i1, 0), 63);
  int j0c = min(max(j0, 0), 63), j1c = min(max(j1, 0), 63);
  const float* Rb = R + (((size_t)b) << 12) * 16;
  float s = mi0 * mj0 * Rb[(size_t)(i0c * 64 + j0c) * 16 + wu0 * 4 + wv0] +
            mi0 * mj1 * Rb[(size_t)(i0c * 64 + j1c) * 16 + wu0 * 4 + wv1] +
            mi1 * mj0 * Rb[(size_t)(i1c * 64 + j0c) * 16 + wu1 * 4 + wv0] +
            mi1 * mj1 * Rb[(size_t)(i1c * 64 + j1c) * 16 + wu1 * 4 + wv1];
  out[(b << 14) + inner] = 1.f / (1.f + __expf(-s));
}

// ---------------------------------------------------------------------------
extern "C" void kernel_launch(void* const* d_in, const int* in_sizes, int n_in,
                              void* d_out, int out_size, void* d_ws, size_t ws_size,
                              hipStream_t stream) {
  const float* x        = (const float*)d_in[0];
  const float* w_dcn    = (const float*)d_in[1];
  const float* b_dcn    = (const float*)d_in[2];
  const float* w_off    = (const float*)d_in[3];
  const float* b_off    = (const float*)d_in[4];
  const float* bn_gamma = (const float*)d_in[5];
  const float* bn_beta  = (const float*)d_in[6];
  const float* bn_mean  = (const float*)d_in[7];
  const float* bn_var   = (const float*)d_in[8];
  const float* w_up     = (const float*)d_in[9];
  const float* w_1x1    = (const float*)d_in[10];
  float* out = (float*)d_out;

  // ws layout in FLOAT units (21.39 MB total):
  float* ws = (float*)d_ws;
  unsigned short* xT     = (unsigned short*)ws;                    // 8388608 ush
  unsigned short* wt_dcn = (unsigned short*)(ws + 4194304);        //  294912 ush
  unsigned short* wt_off = (unsigned short*)(ws + 4341760);        //   73728 ush
  float* vtab            = ws + 4378624;                           //    2048 f
  float* bntab           = ws + 4380672;                           //     256 f
  unsigned short* om     = (unsigned short*)(ws + 4380928);        //  884736 ush
  float* R               = ws + 4823296;                           //  524288 f

  k_prep<<<1152, 256, 0, stream>>>(w_dcn, w_off, b_dcn, bn_gamma, bn_beta,
                                   bn_mean, bn_var, w_up, w_1x1,
                                   wt_dcn, wt_off, vtab, bntab);
  k_xt<<<1024, 256, 0, stream>>>(x, xT);
  k_offconv<<<512, 256, 0, stream>>>(xT, wt_off, b_off, om);
  k_dcn<<<512, 256, 0, stream>>>(xT, wt_dcn, om, vtab, bntab, R);
  k_upb<<<512, 256, 0, stream>>>(R, out);
}

// Round 4
// 163.063 us; speedup vs baseline: 1.9111x; 1.1368x over previous
//
#include <hip/hip_runtime.h>
#include <math.h>

typedef __attribute__((ext_vector_type(8))) short short8;
typedef __attribute__((ext_vector_type(4))) float floatx4;

__device__ __forceinline__ unsigned short bf16r(float f) {
  union { float f; unsigned int u; } v; v.f = f;
  unsigned int u = v.u;
  return (unsigned short)((u + 0x7fffu + ((u >> 16) & 1u)) >> 16);
}
// round-half-up pack (sampling path; 2 ops)
__device__ __forceinline__ unsigned int bf16h(float f) {
  union { float f; unsigned int u; } v; v.f = f;
  return (v.u + 0x8000u) >> 16;
}
__device__ __forceinline__ float bf2f(unsigned int u) {
  union { unsigned int u; float f; } v; v.u = u << 16; return v.f;
}
// async global->LDS DMA, 16B/lane; LDS dst = wave-uniform base + lane*16
__device__ __forceinline__ void glds16(const void* g, void* l) {
  __builtin_amdgcn_global_load_lds(
      (const __attribute__((address_space(1))) unsigned int*)g,
      (__attribute__((address_space(3))) unsigned int*)l, 16, 0, 0);
}

// ---------------------------------------------------------------------------
// K0: weight prep (bf16, lane-linear MFMA-frag layouts) + fused tables
// wt_dcn: element for wave-lane L of tile (s=cg*9+k, ot) at s*4096+ot*512+L*8.
// wt_off: NEW lane-linear phase tiles for the fused offconv prologue:
//   cg*9216 + (k*2+ot)*512 + L*8 + j  ->  w_off[(oc*256+c)*9+k],
//   oc = ot*16+l15 (0 pad for oc>=27), c = cg*32+quad*8+j.
// Both give conflict-free linear ds_read_b128 (addr = base + lane*16B).
// ---------------------------------------------------------------------------
__global__ __launch_bounds__(256) void k_prep(
    const float* __restrict__ w_dcn, const float* __restrict__ w_off,
    const float* __restrict__ b_dcn,
    const float* __restrict__ bn_g, const float* __restrict__ bn_b,
    const float* __restrict__ bn_m, const float* __restrict__ bn_v,
    const float* __restrict__ w_up, const float* __restrict__ w1x1,
    unsigned short* __restrict__ wt_dcn, unsigned short* __restrict__ wt_off,
    float* __restrict__ vtab, float* __restrict__ bntab) {
  int e = blockIdx.x * 256 + threadIdx.x;
  if (e < 294912) {
    int s = e >> 12;            // s = cg*9 + k  (72 tiles of 4096 ush)
    int r = e & 4095;
    int ot = r >> 9;            // 8 output-tiles of 512 ush
    int lane = (r >> 3) & 63;   // wave lane this element feeds
    int j = e & 7;
    int l15 = lane & 15, quad = lane >> 4;
    int o = ot * 16 + l15;
    int k = s % 9, cg = s / 9;
    int c = cg * 32 + quad * 8 + j;
    wt_dcn[e] = bf16r(w_dcn[(o * 256 + c) * 9 + k]);
  }
  if (e < 73728) {
    int cg = e / 9216;
    int r = e % 9216;
    int frag = r >> 9;          // 18 frags: (k,ot)
    int k = frag >> 1, ot = frag & 1;
    int lane = (r >> 3) & 63, j = e & 7;
    int l15 = lane & 15, quad = lane >> 4;
    int oc = ot * 16 + l15;
    int c = cg * 32 + quad * 8 + j;
    wt_off[e] = (oc < 27) ? bf16r(w_off[(oc * 256 + c) * 9 + k]) : (unsigned short)0;
  }
  if (e < 2048) {
    int o = e >> 4;
    vtab[e] = w1x1[o] * w_up[e];
  }
  if (e < 128) {
    float g = bn_g[e] * rsqrtf(bn_v[e] + 1e-5f);
    bntab[e] = g;
    bntab[128 + e] = (b_dcn[e] - bn_m[e]) * g + bn_b[e];
  }
}

// ---------------------------------------------------------------------------
// K0b: x (fp32 NCHW) -> xT (bf16, [b][pixel][c]) via LDS tile transpose
// XCD-swizzled: batch b -> XCD b (blockIdx % 8), so xT lands in the home L2.
// ---------------------------------------------------------------------------
__global__ __launch_bounds__(256) void k_xt(
    const float* __restrict__ x, unsigned short* __restrict__ xT) {
  __shared__ unsigned short sx[32 * 264];
  int b = blockIdx.x & 7, px0 = ((blockIdx.x >> 3) & 127) * 32;
  int t = threadIdx.x;
  int px = t & 31, cg = t >> 5;
  const float* xsrc = x + (((size_t)(b * 256 + cg * 32)) << 12) + px0 + px;
#pragma unroll
  for (int cc = 0; cc < 32; ++cc)
    sx[px * 264 + cg * 32 + cc] = bf16r(xsrc[(size_t)cc << 12]);
  __syncthreads();
#pragma unroll
  for (int j = 0; j < 4; ++j) {
    int unit = t + j * 256;
    int p = unit >> 5, chunk = unit & 31;
    uint4 v = *(const uint4*)&sx[p * 264 + chunk * 8];
    *(uint4*)&xT[((size_t)((b << 12) + px0 + p)) * 256 + chunk * 8] = v;
  }
}

// ---------------------------------------------------------------------------
// K2 (FUSED): offset-conv + DCNv2 MFMA + BN/ReLU + fused (upsample x 1x1) -> R.
// Prologue-A: offset conv for this (b,row) -- glds double-buffered lane-linear
//   wt_off tiles (18.4 KB/cg) into the sW buffers, 18 MFMA/cg, one barrier/cg.
//   Result (27 x 64, bf16 -- identical rounding to the old om global
//   round-trip) goes to LDS 'som'.
// Prologue-B: tap computation reads som (regs-first, barrier, then writes
//   s_ti/s_tw which overlay the som bytes).
// Main loop: R3 structure (proven 53.6us) -- glds double-buffered lane-linear
//   W, one barrier/phase, tap prefetch one phase ahead, zero-weight tap skip.
// XCD-swizzled: batch b -> XCD b (per-batch working set < 4 MiB L2).
// ---------------------------------------------------------------------------
__global__ __launch_bounds__(256, 2) void k_dcn(
    const unsigned short* __restrict__ xT, const unsigned short* __restrict__ wt,
    const unsigned short* __restrict__ wtoff, const float* __restrict__ b_off,
    const float* __restrict__ vtab, const float* __restrict__ bntab,
    float* __restrict__ R) {
  int b = blockIdx.x & 7, row = blockIdx.x >> 3;
  __shared__ unsigned short sW[2 * 12288];   // 49152 B; prologue-A: 2 x 9216-ush
  __shared__ ushort4 s_ti[576];              // 4608 B; first 3456 B = som (bf16)
  __shared__ float4 s_tw[576];               // 9216 B
  int t = threadIdx.x, lane = t & 63, wvx = t >> 6;
  int l15 = lane & 15, quad = lane >> 4;
  int px = wvx * 16 + l15;                   // this thread's pixel column
  const unsigned short* xb = xT + (((size_t)b) << 12) * 256;
  const short8 zz = {0, 0, 0, 0, 0, 0, 0, 0};
  unsigned short* som = (unsigned short*)s_ti;   // 27*64 bf16 = 3456 B

  // ---- prologue-A: offset conv for (b,row) --------------------------------
  {
    // per-k pixel index + validity (same for every cg)
    int pixk[9]; bool vkk[9];
#pragma unroll
    for (int k = 0; k < 9; ++k) {
      int yy = row + k / 3 - 1, xx = px + k % 3 - 1;
      vkk[k] = ((unsigned)yy < 64u) & ((unsigned)xx < 64u);
      pixk[k] = vkk[k] ? (yy * 64 + xx) : 0;
    }
    floatx4 oacc[2];
    oacc[0] = (floatx4){0.f, 0.f, 0.f, 0.f};
    oacc[1] = (floatx4){0.f, 0.f, 0.f, 0.f};

    // stage cg=0 weights (18 frags x 1024 B)
#pragma unroll
    for (int i = 0; i < 5; ++i) {
      int frag = wvx + i * 4;
      if (frag < 18)
        glds16(wtoff + (size_t)frag * 512 + lane * 8, &sW[frag * 512]);
    }
    __syncthreads();   // buf0 weights ready

    for (int cg = 0; cg < 8; ++cg) {
      unsigned short* buf = sW + (cg & 1) * 9216;
      int cb = cg * 32 + quad * 8;
      short8 bx[9];
#pragma unroll
      for (int k = 0; k < 9; ++k) {           // 9 independent gathers in flight
        short8 v = *(const short8*)&xb[(size_t)pixk[k] * 256 + cb];
        bx[k] = vkk[k] ? v : zz;
      }
      if (cg < 7) {                           // stage next cg's weights
        const unsigned short* wsrc = wtoff + (size_t)(cg + 1) * 9216;
        unsigned short* nbuf = sW + ((cg + 1) & 1) * 9216;
#pragma unroll
        for (int i = 0; i < 5; ++i) {
          int frag = wvx + i * 4;
          if (frag < 18)
            glds16(wsrc + (size_t)frag * 512 + lane * 8, &nbuf[frag * 512]);
        }
      }
#pragma unroll
      for (int k = 0; k < 9; ++k) {
        short8 a0 = *(const short8*)&buf[(k * 2 + 0) * 512 + lane * 8];
        short8 a1 = *(const short8*)&buf[(k * 2 + 1) * 512 + lane * 8];
        oacc[0] = __builtin_amdgcn_mfma_f32_16x16x32_bf16(a0, bx[k], oacc[0], 0, 0, 0);
        oacc[1] = __builtin_amdgcn_mfma_f32_16x16x32_bf16(a1, bx[k], oacc[1], 0, 0, 0);
      }
      __syncthreads();   // drains glds(next) + all waves done reading buf
    }
    // write offset/mask row to LDS (bf16 -- identical numerics to old om path)
#pragma unroll
    for (int ot = 0; ot < 2; ++ot)
#pragma unroll
      for (int r = 0; r < 4; ++r) {
        int o = ot * 16 + quad * 4 + r;
        if (o < 27) som[o * 64 + px] = bf16r(oacc[ot][r] + b_off[o]);
      }
    __syncthreads();   // som complete
  }

  // ---- prologue-B: taps = 4 clamped pixel indices + 4 weights per (k,px) ---
  {
    float to1[3], to2[3], tmv[3];
#pragma unroll
    for (int ii = 0; ii < 3; ++ii) {
      int i = t + ii * 256;
      if (i < 576) {
        int k = i >> 6, p = i & 63;
        to1[ii] = bf2f(som[k * 64 + p]);
        to2[ii] = bf2f(som[(9 + k) * 64 + p]);
        tmv[ii] = bf2f(som[(18 + k) * 64 + p]);
      }
    }
    __syncthreads();   // all som reads done before s_ti overwrites those bytes
#pragma unroll
    for (int ii = 0; ii < 3; ++ii) {
      int i = t + ii * 256;
      if (i < 576) {
        int k = i >> 6, p = i & 63;
        float m = 1.f / (1.f + __expf(-tmv[ii]));
        float py = (float)(row + k / 3 - 1) + to1[ii];
        float pxf = (float)(p + (k % 3) - 1) + to2[ii];
        float fy = floorf(py), fx = floorf(pxf);
        int iy = (int)fy, ix = (int)fx;
        float wy1 = py - fy, wy0 = 1.f - wy1;
        float wx1 = pxf - fx, wx0 = 1.f - wx1;
        bool y0ok = (iy >= 0) & (iy < 64), y1ok = (iy >= -1) & (iy < 63);
        bool x0ok = (ix >= 0) & (ix < 64), x1ok = (ix >= -1) & (ix < 63);
        int iy0 = min(max(iy, 0), 63), iy1 = min(max(iy + 1, 0), 63);
        int ix0 = min(max(ix, 0), 63), ix1 = min(max(ix + 1, 0), 63);
        s_ti[i] = make_ushort4((unsigned short)(iy0 * 64 + ix0), (unsigned short)(iy0 * 64 + ix1),
                               (unsigned short)(iy1 * 64 + ix0), (unsigned short)(iy1 * 64 + ix1));
        float4 w;
        w.x = (y0ok && x0ok) ? m * wy0 * wx0 : 0.f;
        w.y = (y0ok && x1ok) ? m * wy0 * wx1 : 0.f;
        w.z = (y1ok && x0ok) ? m * wy1 * wx0 : 0.f;
        w.w = (y1ok && x1ok) ? m * wy1 * wx1 : 0.f;
        s_tw[i] = w;
      }
    }
  }
  __syncthreads();   // s_ti/s_tw ready (read-only hereafter)

  const uint4 z4 = make_uint4(0u, 0u, 0u, 0u);

  floatx4 acc[8];
#pragma unroll
  for (int i = 0; i < 8; ++i) acc[i] = (floatx4){0.f, 0.f, 0.f, 0.f};

  // tap raw data for current phase (prefetched one phase ahead)
  uint4 traw[12];   // [kk][tap]
  {
    int cbase = quad * 8;                       // phase 0: cg=0
#pragma unroll
    for (int kk = 0; kk < 3; ++kk) {
      ushort4 ti = s_ti[(kk << 6) + px];        // phase 0: k = kk
      float4 twn = s_tw[(kk << 6) + px];
      uint4 t0 = z4, t1 = z4, t2 = z4, t3 = z4;
      if (__any(twn.x != 0.f)) t0 = *(const uint4*)&xb[(size_t)ti.x * 256 + cbase];
      if (__any(twn.y != 0.f)) t1 = *(const uint4*)&xb[(size_t)ti.y * 256 + cbase];
      if (__any(twn.z != 0.f)) t2 = *(const uint4*)&xb[(size_t)ti.z * 256 + cbase];
      if (__any(twn.w != 0.f)) t3 = *(const uint4*)&xb[(size_t)ti.w * 256 + cbase];
      traw[kk * 4 + 0] = t0; traw[kk * 4 + 1] = t1;
      traw[kk * 4 + 2] = t2; traw[kk * 4 + 3] = t3;
    }
  }
  {  // glds W(phase 0) -> buf 0
    const unsigned short* wsrc = wt;
#pragma unroll
    for (int i = 0; i < 6; ++i) {
      int blk = wvx * 6 + i;
      glds16(wsrc + (size_t)blk * 512 + lane * 8, &sW[blk * 512]);
    }
  }
  __syncthreads();   // buf0 complete (vmcnt drain) + taps in regs

  int lofs = lane * 8;   // lane-linear A-frag offset (ushorts)

  for (int phase = 0; phase < 24; ++phase) {
    unsigned short* buf = sW + (phase & 1) * 12288;
    unsigned short* nbuf = sW + ((phase + 1) & 1) * 12288;
    // issue next W DMA first (overlaps everything below)
    if (phase < 23) {
      const unsigned short* wsrc = wt + (size_t)(phase + 1) * 12288;
#pragma unroll
      for (int i = 0; i < 6; ++i) {
        int blk = wvx * 6 + i;
        glds16(wsrc + (size_t)blk * 512 + lane * 8, &nbuf[blk * 512]);
      }
    }
    int nphase = phase + 1;
    int ncbase = (nphase / 3) * 32 + quad * 8;

#pragma unroll
    for (int kk = 0; kk < 3; ++kk) {
      int k = (phase % 3) * 3 + kk;
      // current-phase tap weights + raw data (prefetched)
      float4 tw = s_tw[(k << 6) + px];
      union { uint4 u; short8 s; } x0, x1, x2, x3;
      x0.u = traw[kk * 4 + 0]; x1.u = traw[kk * 4 + 1];
      x2.u = traw[kk * 4 + 2]; x3.u = traw[kk * 4 + 3];
      // prefetch taps for next phase into same slots (consumed above),
      // skipping gathers whose weights are zero across the wave
      if (phase < 23) {
        int nk = (nphase % 3) * 3 + kk;
        ushort4 ti = s_ti[(nk << 6) + px];
        float4 twn = s_tw[(nk << 6) + px];
        uint4 t0 = z4, t1 = z4, t2 = z4, t3 = z4;
        if (__any(twn.x != 0.f)) t0 = *(const uint4*)&xb[(size_t)ti.x * 256 + ncbase];
        if (__any(twn.y != 0.f)) t1 = *(const uint4*)&xb[(size_t)ti.y * 256 + ncbase];
        if (__any(twn.z != 0.f)) t2 = *(const uint4*)&xb[(size_t)ti.z * 256 + ncbase];
        if (__any(twn.w != 0.f)) t3 = *(const uint4*)&xb[(size_t)ti.w * 256 + ncbase];
        traw[kk * 4 + 0] = t0; traw[kk * 4 + 1] = t1;
        traw[kk * 4 + 2] = t2; traw[kk * 4 + 3] = t3;
      }
      // sampling: tap0 always; taps 1-3 skipped when wave-uniformly zero
      float r[8];
#pragma unroll
      for (int j = 0; j < 8; ++j) r[j] = tw.x * bf2f((unsigned short)x0.s[j]);
      if (__any(tw.y != 0.f)) {
#pragma unroll
        for (int j = 0; j < 8; ++j) r[j] += tw.y * bf2f((unsigned short)x1.s[j]);
      }
      if (__any(tw.z != 0.f)) {
#pragma unroll
        for (int j = 0; j < 8; ++j) r[j] += tw.z * bf2f((unsigned short)x2.s[j]);
      }
      if (__any(tw.w != 0.f)) {
#pragma unroll
        for (int j = 0; j < 8; ++j) r[j] += tw.w * bf2f((unsigned short)x3.s[j]);
      }
      union { uint4 u; short8 s; } bu;
      bu.u = make_uint4(bf16h(r[0]) | (bf16h(r[1]) << 16), bf16h(r[2]) | (bf16h(r[3]) << 16),
                        bf16h(r[4]) | (bf16h(r[5]) << 16), bf16h(r[6]) | (bf16h(r[7]) << 16));
      // MFMA for this kk; lane-linear A-frag reads (conflict-free)
      const unsigned short* bk = buf + kk * 4096 + lofs;
#pragma unroll
      for (int ot = 0; ot < 8; ++ot) {
        short8 af = *(const short8*)&bk[ot * 512];
        acc[ot] = __builtin_amdgcn_mfma_f32_16x16x32_bf16(af, bu.s, acc[ot], 0, 0, 0);
      }
    }
    __syncthreads();  // drains glds(next) + all waves done reading buf
  }

  // epilogue: BN+ReLU then R_t[px] = sum_o v[o][t]*yv, reduced over quads
  float* sv = (float*)sW;          // 128*17 vtab (stride 17: conflict-free) + bn
  float* sbn = sv + 2176;
  for (int i = t; i < 2048; i += 256) sv[(i >> 4) * 17 + (i & 15)] = vtab[i];
  if (t < 256) sbn[t] = bntab[t];
  __syncthreads();

  float rpart[16];
#pragma unroll
  for (int i = 0; i < 16; ++i) rpart[i] = 0.f;
#pragma unroll
  for (int ot = 0; ot < 8; ++ot)
#pragma unroll
    for (int r = 0; r < 4; ++r) {
      int o = ot * 16 + quad * 4 + r;
      float yv = fmaxf(acc[ot][r] * sbn[o] + sbn[128 + o], 0.f);
      const float* vp = &sv[o * 17];
#pragma unroll
      for (int tt = 0; tt < 16; ++tt) rpart[tt] += vp[tt] * yv;
    }
#pragma unroll
  for (int tt = 0; tt < 16; ++tt) {
    rpart[tt] += __shfl_xor(rpart[tt], 16, 64);
    rpart[tt] += __shfl_xor(rpart[tt], 32, 64);
  }
  size_t rbase = ((size_t)((b << 12) + row * 64 + px)) * 16;
#pragma unroll
  for (int j = 0; j < 4; ++j) R[rbase + quad * 4 + j] = rpart[quad * 4 + j];
}

// ---------------------------------------------------------------------------
// K3: upsample+1x1+sigmoid from R maps: 4 loads + sigmoid per output
// XCD-swizzled: batch b -> XCD b, R reads hit the home L2.
// ---------------------------------------------------------------------------
__global__ __launch_bounds__(256) void k_upb(
    const float* __restrict__ R, float* __restrict__ out) {
  int b = blockIdx.x & 7, sub = blockIdx.x >> 3;
  int inner = sub * 256 + threadIdx.x;        // 0..16383
  int X = inner & 127, Y = inner >> 7;        // Y 0..127
  int i0, wu0, wu1, j0, wv0, wv1;
  if (Y & 1) { i0 = (Y - 1) >> 1; wu0 = 2; wu1 = 0; }
  else       { i0 = (Y - 2) / 2;  wu0 = 3; wu1 = 1; }
  if (X & 1) { j0 = (X - 1) >> 1; wv0 = 2; wv1 = 0; }
  else       { j0 = (X - 2) / 2;  wv0 = 3; wv1 = 1; }
  int i1 = i0 + 1, j1 = j0 + 1;
  float mi0 = ((unsigned)i0 < 64u) ? 1.f : 0.f;
  float mi1 = ((unsigned)i1 < 64u) ? 1.f : 0.f;
  float mj0 = ((unsigned)j0 < 64u) ? 1.f : 0.f;
  float mj1 = ((unsigned)j1 < 64u) ? 1.f : 0.f;
  int i0c = min(max(i0, 0), 63), i1c = min(max(i1, 0), 63);
  int j0c = min(max(j0, 0), 63), j1c = min(max(j1, 0), 63);
  const float* Rb = R + (((size_t)b) << 12) * 16;
  float s = mi0 * mj0 * Rb[(size_t)(i0c * 64 + j0c) * 16 + wu0 * 4 + wv0] +
            mi0 * mj1 * Rb[(size_t)(i0c * 64 + j1c) * 16 + wu0 * 4 + wv1] +
            mi1 * mj0 * Rb[(size_t)(i1c * 64 + j0c) * 16 + wu1 * 4 + wv0] +
            mi1 * mj1 * Rb[(size_t)(i1c * 64 + j1c) * 16 + wu1 * 4 + wv1];
  out[(b << 14) + inner] = 1.f / (1.f + __expf(-s));
}

// ---------------------------------------------------------------------------
extern "C" void kernel_launch(void* const* d_in, const int* in_sizes, int n_in,
                              void* d_out, int out_size, void* d_ws, size_t ws_size,
                              hipStream_t stream) {
  const float* x        = (const float*)d_in[0];
  const float* w_dcn    = (const float*)d_in[1];
  const float* b_dcn    = (const float*)d_in[2];
  const float* w_off    = (const float*)d_in[3];
  const float* b_off    = (const float*)d_in[4];
  const float* bn_gamma = (const float*)d_in[5];
  const float* bn_beta  = (const float*)d_in[6];
  const float* bn_mean  = (const float*)d_in[7];
  const float* bn_var   = (const float*)d_in[8];
  const float* w_up     = (const float*)d_in[9];
  const float* w_1x1    = (const float*)d_in[10];
  float* out = (float*)d_out;

  // ws layout in FLOAT units:
  float* ws = (float*)d_ws;
  unsigned short* xT     = (unsigned short*)ws;                    // 8388608 ush
  unsigned short* wt_dcn = (unsigned short*)(ws + 4194304);        //  294912 ush
  unsigned short* wt_off = (unsigned short*)(ws + 4341760);        //   73728 ush
  float* vtab            = ws + 4378624;                           //    2048 f
  float* bntab           = ws + 4380672;                           //     256 f
  float* R               = ws + 4823296;                           //  524288 f

  k_prep<<<1152, 256, 0, stream>>>(w_dcn, w_off, b_dcn, bn_gamma, bn_beta,
                                   bn_mean, bn_var, w_up, w_1x1,
                                   wt_dcn, wt_off, vtab, bntab);
  k_xt<<<1024, 256, 0, stream>>>(x, xT);
  k_dcn<<<512, 256, 0, stream>>>(xT, wt_dcn, wt_off, b_off, vtab, bntab, R);
  k_upb<<<512, 256, 0, stream>>>(R, out);
}

// Round 5
// 146.354 us; speedup vs baseline: 2.1293x; 1.1142x over previous
//
#include <hip/hip_runtime.h>
#include <math.h>

typedef __attribute__((ext_vector_type(8))) short short8;
typedef __attribute__((ext_vector_type(4))) float floatx4;

__device__ __forceinline__ unsigned short bf16r(float f) {
  union { float f; unsigned int u; } v; v.f = f;
  unsigned int u = v.u;
  return (unsigned short)((u + 0x7fffu + ((u >> 16) & 1u)) >> 16);
}
// round-half-up pack (sampling path; 2 ops)
__device__ __forceinline__ unsigned int bf16h(float f) {
  union { float f; unsigned int u; } v; v.f = f;
  return (v.u + 0x8000u) >> 16;
}
__device__ __forceinline__ float bf2f(unsigned int u) {
  union { unsigned int u; float f; } v; v.u = u << 16; return v.f;
}
// async global->LDS DMA, 16B/lane; LDS dst = wave-uniform base + lane*16
__device__ __forceinline__ void glds16(const void* g, void* l) {
  __builtin_amdgcn_global_load_lds(
      (const __attribute__((address_space(1))) unsigned int*)g,
      (__attribute__((address_space(3))) unsigned int*)l, 16, 0, 0);
}

// ---------------------------------------------------------------------------
// K0 (MERGED prep + xT): weight prep (bf16, lane-linear MFMA-frag layouts),
// fused tables, w_off-nonzero flags, and the x->xT transpose.
// Blocks 0-1023 additionally do the xT tile (b = blockIdx&7 -> XCD b).
// offflags[blk*4+wave] = 1 iff any w_off element seen by that wave != 0
// (blocks 0-287 cover all 73728 w_off slots; unconditional writes -> no
// memset / atomics needed).
// ---------------------------------------------------------------------------
__global__ __launch_bounds__(256) void k_pre(
    const float* __restrict__ x,
    const float* __restrict__ w_dcn, const float* __restrict__ w_off,
    const float* __restrict__ b_dcn,
    const float* __restrict__ bn_g, const float* __restrict__ bn_b,
    const float* __restrict__ bn_m, const float* __restrict__ bn_v,
    const float* __restrict__ w_up, const float* __restrict__ w1x1,
    unsigned short* __restrict__ xT,
    unsigned short* __restrict__ wt_dcn, unsigned short* __restrict__ wt_off,
    float* __restrict__ vtab, float* __restrict__ bntab,
    unsigned int* __restrict__ offflags) {
  __shared__ unsigned short sx[32 * 264];
  int e = blockIdx.x * 256 + threadIdx.x;
  // ---- prep slices ----
  if (e < 294912) {
    int s = e >> 12;            // s = cg*9 + k  (72 tiles of 4096 ush)
    int r = e & 4095;
    int ot = r >> 9;            // 8 output-tiles of 512 ush
    int lane = (r >> 3) & 63;   // wave lane this element feeds
    int j = e & 7;
    int l15 = lane & 15, quad = lane >> 4;
    int o = ot * 16 + l15;
    int k = s % 9, cg = s / 9;
    int c = cg * 32 + quad * 8 + j;
    wt_dcn[e] = bf16r(w_dcn[(o * 256 + c) * 9 + k]);
  }
  bool nz = false;
  if (e < 73728) {
    int cg = e / 9216;
    int r = e % 9216;
    int frag = r >> 9;          // 18 frags: (k,ot)
    int k = frag >> 1, ot = frag & 1;
    int lane = (r >> 3) & 63, j = e & 7;
    int l15 = lane & 15, quad = lane >> 4;
    int oc = ot * 16 + l15;
    int c = cg * 32 + quad * 8 + j;
    float wv = (oc < 27) ? w_off[(oc * 256 + c) * 9 + k] : 0.f;
    wt_off[e] = bf16r(wv);
    nz = (wv != 0.f);
  }
  unsigned long long ba = __ballot(nz);
  if (blockIdx.x < 288 && (threadIdx.x & 63) == 0)
    offflags[blockIdx.x * 4 + (threadIdx.x >> 6)] = (ba != 0ull) ? 1u : 0u;
  if (e < 2048) {
    int o = e >> 4;
    vtab[e] = w1x1[o] * w_up[e];
  }
  if (e < 128) {
    float g = bn_g[e] * rsqrtf(bn_v[e] + 1e-5f);
    bntab[e] = g;
    bntab[128 + e] = (b_dcn[e] - bn_m[e]) * g + bn_b[e];
  }
  // ---- xT transpose (blocks 0-1023) ----
  if (blockIdx.x < 1024) {
    int b = blockIdx.x & 7, px0 = ((blockIdx.x >> 3) & 127) * 32;
    int t = threadIdx.x;
    int px = t & 31, cg = t >> 5;
    const float* xsrc = x + (((size_t)(b * 256 + cg * 32)) << 12) + px0 + px;
#pragma unroll
    for (int cc = 0; cc < 32; ++cc)
      sx[px * 264 + cg * 32 + cc] = bf16r(xsrc[(size_t)cc << 12]);
    __syncthreads();
#pragma unroll
    for (int j = 0; j < 4; ++j) {
      int unit = t + j * 256;
      int p = unit >> 5, chunk = unit & 31;
      uint4 v = *(const uint4*)&sx[p * 264 + chunk * 8];
      *(uint4*)&xT[((size_t)((b << 12) + px0 + p)) * 256 + chunk * 8] = v;
    }
  }
}

// ---------------------------------------------------------------------------
// K2 (FUSED): offset-conv + DCNv2 MFMA + BN/ReLU + fused (upsample x 1x1) -> R.
// FAST PATH (offflags all zero, i.e. w_off == 0): om = b_off exactly (MFMA
//   with zero A is exactly 0), so prologue-A (the 49us of scattered gathers)
//   is skipped and taps come from bf16r(b_off) -- bit-identical numerics.
// SLOW PATH: R4 structure (glds double-buffered lane-linear wt_off tiles,
//   18 MFMA/cg, one barrier/cg) -> som in LDS.
// Main loop: R3 structure (proven 53.6us) -- glds double-buffered lane-linear
//   W, one barrier/phase, tap prefetch one phase ahead, zero-weight tap skip.
// R output layout: [b][slot(16)][pixel(4096)] planes -> 4-line stores here
//   and coalesced loads in k_upb.
// XCD-swizzled: batch b -> XCD b (per-batch working set < 4 MiB L2).
// ---------------------------------------------------------------------------
__global__ __launch_bounds__(256, 2) void k_dcn(
    const unsigned short* __restrict__ xT, const unsigned short* __restrict__ wt,
    const unsigned short* __restrict__ wtoff, const float* __restrict__ b_off,
    const float* __restrict__ vtab, const float* __restrict__ bntab,
    const unsigned int* __restrict__ offflags, float* __restrict__ R) {
  int b = blockIdx.x & 7, row = blockIdx.x >> 3;
  __shared__ unsigned short sW[2 * 12288];   // 49152 B; prologue-A: 2 x 9216-ush
  __shared__ ushort4 s_ti[576];              // 4608 B; first 3456 B = som (bf16)
  __shared__ float4 s_tw[576];               // 9216 B
  __shared__ unsigned int s_fl[4];
  int t = threadIdx.x, lane = t & 63, wvx = t >> 6;
  int l15 = lane & 15, quad = lane >> 4;
  int px = wvx * 16 + l15;                   // this thread's pixel column
  const unsigned short* xb = xT + (((size_t)b) << 12) * 256;
  const short8 zz = {0, 0, 0, 0, 0, 0, 0, 0};
  unsigned short* som = (unsigned short*)s_ti;   // 27*64 bf16 = 3456 B

  // ---- w_off-nonzero flag (grid-uniform) ----------------------------------
  {
    unsigned int a = 0;
    for (int i = t; i < 1152; i += 256) a |= offflags[i];
    a = __any(a != 0u) ? 1u : 0u;
    if (lane == 0) s_fl[wvx] = a;
  }
  __syncthreads();
  const bool offnz = (s_fl[0] | s_fl[1] | s_fl[2] | s_fl[3]) != 0u;

  // ---- prologue-A (slow path only): offset conv for (b,row) ---------------
  if (offnz) {
    int pixk[9]; bool vkk[9];
#pragma unroll
    for (int k = 0; k < 9; ++k) {
      int yy = row + k / 3 - 1, xx = px + k % 3 - 1;
      vkk[k] = ((unsigned)yy < 64u) & ((unsigned)xx < 64u);
      pixk[k] = vkk[k] ? (yy * 64 + xx) : 0;
    }
    floatx4 oacc[2];
    oacc[0] = (floatx4){0.f, 0.f, 0.f, 0.f};
    oacc[1] = (floatx4){0.f, 0.f, 0.f, 0.f};

#pragma unroll
    for (int i = 0; i < 5; ++i) {
      int frag = wvx + i * 4;
      if (frag < 18)
        glds16(wtoff + (size_t)frag * 512 + lane * 8, &sW[frag * 512]);
    }
    __syncthreads();   // buf0 weights ready

    for (int cg = 0; cg < 8; ++cg) {
      unsigned short* buf = sW + (cg & 1) * 9216;
      int cb = cg * 32 + quad * 8;
      short8 bx[9];
#pragma unroll
      for (int k = 0; k < 9; ++k) {
        short8 v = *(const short8*)&xb[(size_t)pixk[k] * 256 + cb];
        bx[k] = vkk[k] ? v : zz;
      }
      if (cg < 7) {
        const unsigned short* wsrc = wtoff + (size_t)(cg + 1) * 9216;
        unsigned short* nbuf = sW + ((cg + 1) & 1) * 9216;
#pragma unroll
        for (int i = 0; i < 5; ++i) {
          int frag = wvx + i * 4;
          if (frag < 18)
            glds16(wsrc + (size_t)frag * 512 + lane * 8, &nbuf[frag * 512]);
        }
      }
#pragma unroll
      for (int k = 0; k < 9; ++k) {
        short8 a0 = *(const short8*)&buf[(k * 2 + 0) * 512 + lane * 8];
        short8 a1 = *(const short8*)&buf[(k * 2 + 1) * 512 + lane * 8];
        oacc[0] = __builtin_amdgcn_mfma_f32_16x16x32_bf16(a0, bx[k], oacc[0], 0, 0, 0);
        oacc[1] = __builtin_amdgcn_mfma_f32_16x16x32_bf16(a1, bx[k], oacc[1], 0, 0, 0);
      }
      __syncthreads();
    }
#pragma unroll
    for (int ot = 0; ot < 2; ++ot)
#pragma unroll
      for (int r = 0; r < 4; ++r) {
        int o = ot * 16 + quad * 4 + r;
        if (o < 27) som[o * 64 + px] = bf16r(oacc[ot][r] + b_off[o]);
      }
    __syncthreads();   // som complete
  }

  // ---- prologue-B: taps = 4 clamped pixel indices + 4 weights per (k,px) ---
  {
    float to1[3], to2[3], tmv[3];
    if (offnz) {
#pragma unroll
      for (int ii = 0; ii < 3; ++ii) {
        int i = t + ii * 256;
        if (i < 576) {
          int k = i >> 6, p = i & 63;
          to1[ii] = bf2f(som[k * 64 + p]);
          to2[ii] = bf2f(som[(9 + k) * 64 + p]);
          tmv[ii] = bf2f(som[(18 + k) * 64 + p]);
        }
      }
      __syncthreads();   // all som reads done before s_ti overwrites
    } else {
#pragma unroll
      for (int ii = 0; ii < 3; ++ii) {
        int i = t + ii * 256;
        if (i < 576) {
          int k = i >> 6;
          to1[ii] = bf2f(bf16r(b_off[k]));        // == bf16r(0 + b_off)
          to2[ii] = bf2f(bf16r(b_off[9 + k]));
          tmv[ii] = bf2f(bf16r(b_off[18 + k]));
        }
      }
    }
#pragma unroll
    for (int ii = 0; ii < 3; ++ii) {
      int i = t + ii * 256;
      if (i < 576) {
        int k = i >> 6, p = i & 63;
        float m = 1.f / (1.f + __expf(-tmv[ii]));
        float py = (float)(row + k / 3 - 1) + to1[ii];
        float pxf = (float)(p + (k % 3) - 1) + to2[ii];
        float fy = floorf(py), fx = floorf(pxf);
        int iy = (int)fy, ix = (int)fx;
        float wy1 = py - fy, wy0 = 1.f - wy1;
        float wx1 = pxf - fx, wx0 = 1.f - wx1;
        bool y0ok = (iy >= 0) & (iy < 64), y1ok = (iy >= -1) & (iy < 63);
        bool x0ok = (ix >= 0) & (ix < 64), x1ok = (ix >= -1) & (ix < 63);
        int iy0 = min(max(iy, 0), 63), iy1 = min(max(iy + 1, 0), 63);
        int ix0 = min(max(ix, 0), 63), ix1 = min(max(ix + 1, 0), 63);
        s_ti[i] = make_ushort4((unsigned short)(iy0 * 64 + ix0), (unsigned short)(iy0 * 64 + ix1),
                               (unsigned short)(iy1 * 64 + ix0), (unsigned short)(iy1 * 64 + ix1));
        float4 w;
        w.x = (y0ok && x0ok) ? m * wy0 * wx0 : 0.f;
        w.y = (y0ok && x1ok) ? m * wy0 * wx1 : 0.f;
        w.z = (y1ok && x0ok) ? m * wy1 * wx0 : 0.f;
        w.w = (y1ok && x1ok) ? m * wy1 * wx1 : 0.f;
        s_tw[i] = w;
      }
    }
  }
  __syncthreads();   // s_ti/s_tw ready (read-only hereafter)

  const uint4 z4 = make_uint4(0u, 0u, 0u, 0u);

  floatx4 acc[8];
#pragma unroll
  for (int i = 0; i < 8; ++i) acc[i] = (floatx4){0.f, 0.f, 0.f, 0.f};

  // tap raw data for current phase (prefetched one phase ahead)
  uint4 traw[12];   // [kk][tap]
  {
    int cbase = quad * 8;                       // phase 0: cg=0
#pragma unroll
    for (int kk = 0; kk < 3; ++kk) {
      ushort4 ti = s_ti[(kk << 6) + px];        // phase 0: k = kk
      float4 twn = s_tw[(kk << 6) + px];
      uint4 t0 = z4, t1 = z4, t2 = z4, t3 = z4;
      if (__any(twn.x != 0.f)) t0 = *(const uint4*)&xb[(size_t)ti.x * 256 + cbase];
      if (__any(twn.y != 0.f)) t1 = *(const uint4*)&xb[(size_t)ti.y * 256 + cbase];
      if (__any(twn.z != 0.f)) t2 = *(const uint4*)&xb[(size_t)ti.z * 256 + cbase];
      if (__any(twn.w != 0.f)) t3 = *(const uint4*)&xb[(size_t)ti.w * 256 + cbase];
      traw[kk * 4 + 0] = t0; traw[kk * 4 + 1] = t1;
      traw[kk * 4 + 2] = t2; traw[kk * 4 + 3] = t3;
    }
  }
  {  // glds W(phase 0) -> buf 0
    const unsigned short* wsrc = wt;
#pragma unroll
    for (int i = 0; i < 6; ++i) {
      int blk = wvx * 6 + i;
      glds16(wsrc + (size_t)blk * 512 + lane * 8, &sW[blk * 512]);
    }
  }
  __syncthreads();   // buf0 complete (vmcnt drain) + taps in regs

  int lofs = lane * 8;   // lane-linear A-frag offset (ushorts)

  for (int phase = 0; phase < 24; ++phase) {
    unsigned short* buf = sW + (phase & 1) * 12288;
    unsigned short* nbuf = sW + ((phase + 1) & 1) * 12288;
    // issue next W DMA first (overlaps everything below)
    if (phase < 23) {
      const unsigned short* wsrc = wt + (size_t)(phase + 1) * 12288;
#pragma unroll
      for (int i = 0; i < 6; ++i) {
        int blk = wvx * 6 + i;
        glds16(wsrc + (size_t)blk * 512 + lane * 8, &nbuf[blk * 512]);
      }
    }
    int nphase = phase + 1;
    int ncbase = (nphase / 3) * 32 + quad * 8;

#pragma unroll
    for (int kk = 0; kk < 3; ++kk) {
      int k = (phase % 3) * 3 + kk;
      // current-phase tap weights + raw data (prefetched)
      float4 tw = s_tw[(k << 6) + px];
      union { uint4 u; short8 s; } x0, x1, x2, x3;
      x0.u = traw[kk * 4 + 0]; x1.u = traw[kk * 4 + 1];
      x2.u = traw[kk * 4 + 2]; x3.u = traw[kk * 4 + 3];
      // prefetch taps for next phase into same slots (consumed above),
      // skipping gathers whose weights are zero across the wave
      if (phase < 23) {
        int nk = (nphase % 3) * 3 + kk;
        ushort4 ti = s_ti[(nk << 6) + px];
        float4 twn = s_tw[(nk << 6) + px];
        uint4 t0 = z4, t1 = z4, t2 = z4, t3 = z4;
        if (__any(twn.x != 0.f)) t0 = *(const uint4*)&xb[(size_t)ti.x * 256 + ncbase];
        if (__any(twn.y != 0.f)) t1 = *(const uint4*)&xb[(size_t)ti.y * 256 + ncbase];
        if (__any(twn.z != 0.f)) t2 = *(const uint4*)&xb[(size_t)ti.z * 256 + ncbase];
        if (__any(twn.w != 0.f)) t3 = *(const uint4*)&xb[(size_t)ti.w * 256 + ncbase];
        traw[kk * 4 + 0] = t0; traw[kk * 4 + 1] = t1;
        traw[kk * 4 + 2] = t2; traw[kk * 4 + 3] = t3;
      }
      // sampling: tap0 always; taps 1-3 skipped when wave-uniformly zero
      float r[8];
#pragma unroll
      for (int j = 0; j < 8; ++j) r[j] = tw.x * bf2f((unsigned short)x0.s[j]);
      if (__any(tw.y != 0.f)) {
#pragma unroll
        for (int j = 0; j < 8; ++j) r[j] += tw.y * bf2f((unsigned short)x1.s[j]);
      }
      if (__any(tw.z != 0.f)) {
#pragma unroll
        for (int j = 0; j < 8; ++j) r[j] += tw.z * bf2f((unsigned short)x2.s[j]);
      }
      if (__any(tw.w != 0.f)) {
#pragma unroll
        for (int j = 0; j < 8; ++j) r[j] += tw.w * bf2f((unsigned short)x3.s[j]);
      }
      union { uint4 u; short8 s; } bu;
      bu.u = make_uint4(bf16h(r[0]) | (bf16h(r[1]) << 16), bf16h(r[2]) | (bf16h(r[3]) << 16),
                        bf16h(r[4]) | (bf16h(r[5]) << 16), bf16h(r[6]) | (bf16h(r[7]) << 16));
      // MFMA for this kk; lane-linear A-frag reads (conflict-free)
      const unsigned short* bk = buf + kk * 4096 + lofs;
#pragma unroll
      for (int ot = 0; ot < 8; ++ot) {
        short8 af = *(const short8*)&bk[ot * 512];
        acc[ot] = __builtin_amdgcn_mfma_f32_16x16x32_bf16(af, bu.s, acc[ot], 0, 0, 0);
      }
    }
    __syncthreads();  // drains glds(next) + all waves done reading buf
  }

  // epilogue: BN+ReLU then R[slot][px] = sum_o v[o][slot]*yv, reduced over quads
  float* sv = (float*)sW;          // 128*17 vtab (stride 17: conflict-free) + bn
  float* sbn = sv + 2176;
  for (int i = t; i < 2048; i += 256) sv[(i >> 4) * 17 + (i & 15)] = vtab[i];
  if (t < 256) sbn[t] = bntab[t];
  __syncthreads();

  float rpart[16];
#pragma unroll
  for (int i = 0; i < 16; ++i) rpart[i] = 0.f;
#pragma unroll
  for (int ot = 0; ot < 8; ++ot)
#pragma unroll
    for (int r = 0; r < 4; ++r) {
      int o = ot * 16 + quad * 4 + r;
      float yv = fmaxf(acc[ot][r] * sbn[o] + sbn[128 + o], 0.f);
      const float* vp = &sv[o * 17];
#pragma unroll
      for (int tt = 0; tt < 16; ++tt) rpart[tt] += vp[tt] * yv;
    }
#pragma unroll
  for (int tt = 0; tt < 16; ++tt) {
    rpart[tt] += __shfl_xor(rpart[tt], 16, 64);
    rpart[tt] += __shfl_xor(rpart[tt], 32, 64);
  }
  // R planes: [b][slot][pixel] -> 4-line coalesced stores
#pragma unroll
  for (int j = 0; j < 4; ++j) {
    int slot = quad * 4 + j;
    R[(((size_t)(b * 16 + slot)) << 12) + row * 64 + px] = rpart[slot];
  }
}

// ---------------------------------------------------------------------------
// K3: upsample+1x1+sigmoid from R planes: 4 coalesced loads + sigmoid
// XCD-swizzled: batch b -> XCD b, R reads hit the home L2.
// ---------------------------------------------------------------------------
__global__ __launch_bounds__(256) void k_upb(
    const float* __restrict__ R, float* __restrict__ out) {
  int b = blockIdx.x & 7, sub = blockIdx.x >> 3;
  int inner = sub * 256 + threadIdx.x;        // 0..16383
  int X = inner & 127, Y = inner >> 7;        // Y 0..127
  int i0, wu0, wu1, j0, wv0, wv1;
  if (Y & 1) { i0 = (Y - 1) >> 1; wu0 = 2; wu1 = 0; }
  else       { i0 = (Y - 2) / 2;  wu0 = 3; wu1 = 1; }
  if (X & 1) { j0 = (X - 1) >> 1; wv0 = 2; wv1 = 0; }
  else       { j0 = (X - 2) / 2;  wv0 = 3; wv1 = 1; }
  int i1 = i0 + 1, j1 = j0 + 1;
  float mi0 = ((unsigned)i0 < 64u) ? 1.f : 0.f;
  float mi1 = ((unsigned)i1 < 64u) ? 1.f : 0.f;
  float mj0 = ((unsigned)j0 < 64u) ? 1.f : 0.f;
  float mj1 = ((unsigned)j1 < 64u) ? 1.f : 0.f;
  int i0c = min(max(i0, 0), 63), i1c = min(max(i1, 0), 63);
  int j0c = min(max(j0, 0), 63), j1c = min(max(j1, 0), 63);
  const float* Rb = R + (((size_t)b) << 16);   // b*16*4096
  float s = mi0 * mj0 * Rb[((wu0 * 4 + wv0) << 12) + (i0c << 6) + j0c] +
            mi0 * mj1 * Rb[((wu0 * 4 + wv1) << 12) + (i0c << 6) + j1c] +
            mi1 * mj0 * Rb[((wu1 * 4 + wv0) << 12) + (i1c << 6) + j0c] +
            mi1 * mj1 * Rb[((wu1 * 4 + wv1) << 12) + (i1c << 6) + j1c];
  out[(b << 14) + inner] = 1.f / (1.f + __expf(-s));
}

// ---------------------------------------------------------------------------
extern "C" void kernel_launch(void* const* d_in, const int* in_sizes, int n_in,
                              void* d_out, int out_size, void* d_ws, size_t ws_size,
                              hipStream_t stream) {
  const float* x        = (const float*)d_in[0];
  const float* w_dcn    = (const float*)d_in[1];
  const float* b_dcn    = (const float*)d_in[2];
  const float* w_off    = (const float*)d_in[3];
  const float* b_off    = (const float*)d_in[4];
  const float* bn_gamma = (const float*)d_in[5];
  const float* bn_beta  = (const float*)d_in[6];
  const float* bn_mean  = (const float*)d_in[7];
  const float* bn_var   = (const float*)d_in[8];
  const float* w_up     = (const float*)d_in[9];
  const float* w_1x1    = (const float*)d_in[10];
  float* out = (float*)d_out;

  // ws layout in FLOAT units:
  float* ws = (float*)d_ws;
  unsigned short* xT     = (unsigned short*)ws;                    // 8388608 ush
  unsigned short* wt_dcn = (unsigned short*)(ws + 4194304);        //  294912 ush
  unsigned short* wt_off = (unsigned short*)(ws + 4341760);        //   73728 ush
  float* vtab            = ws + 4378624;                           //    2048 f
  float* bntab           = ws + 4380672;                           //     256 f
  unsigned int* offflags = (unsigned int*)(ws + 4380928);          //    1152 u32
  float* R               = ws + 4823296;                           //  524288 f

  k_pre<<<1152, 256, 0, stream>>>(x, w_dcn, w_off, b_dcn, bn_gamma, bn_beta,
                                  bn_mean, bn_var, w_up, w_1x1,
                                  xT, wt_dcn, wt_off, vtab, bntab, offflags);
  k_dcn<<<512, 256, 0, stream>>>(xT, wt_dcn, wt_off, b_off, vtab, bntab,
                                 offflags, R);
  k_upb<<<512, 256, 0, stream>>>(R, out);
}